// Round 13
// baseline (85.943 us; speedup 1.0000x reference)
//
#include <hip/hip_runtime.h>

#define BN_EPS 1e-5f
#define ALPHA 0.5f
#define BETA 0.5f

// B=32, C=1024, W=32, H=32, K=2.
// 2 dispatches, no memset, no atomics:
//   k_conv : conv(C->1) + BN + ReLU + per-(b,row) partial strip sums,
//            one plain float4 store per block -> part[b*32+row]
//   k_out  : per-wave factor recomputation + elementwise pass.
//            Plain loads (MALL hits on fm re-read), builtin NT stores
//            (A/B proven vs plain; sc1-asm probe FAILED correctness in R12).
//            4096 blocks x 256 threads, contiguous 32 KB span per block
//            (8 float4/thread in flight — span-size probe this round).
//
// ws byte layout:
//   part [32*32] float4 @ 0  (16 KB)  {row_w_sum, h0_sum, h1_sum, 0}

typedef float vfloat4 __attribute__((ext_vector_type(4)));

__global__ __launch_bounds__(256) void k_conv(
    const float* __restrict__ fm, const float* __restrict__ wW,
    const float* __restrict__ wH, const float* __restrict__ bw,
    const float* __restrict__ gw, const float* __restrict__ betw,
    const float* __restrict__ mw, const float* __restrict__ vw,
    const float* __restrict__ bh, const float* __restrict__ gh,
    const float* __restrict__ beth, const float* __restrict__ mh,
    const float* __restrict__ vh, float4* __restrict__ part) {
  __shared__ float lw[1024];
  __shared__ float lh[1024];
  __shared__ float4 part_w[32][8];
  __shared__ float4 part_h[32][8];

  const int t = threadIdx.x;
  const int b = blockIdx.x >> 5;    // batch
  const int row = blockIdx.x & 31;  // w row

  {
    reinterpret_cast<float4*>(lw)[t] = reinterpret_cast<const float4*>(wW)[t];
    reinterpret_cast<float4*>(lh)[t] = reinterpret_cast<const float4*>(wH)[t];
  }
  __syncthreads();

  const int c_off = t >> 3;  // channel within 32-group
  const int s4 = t & 7;      // float4 within the row (h)
  const vfloat4* f4 = reinterpret_cast<const vfloat4*>(fm) +
                      ((size_t)(b * 1024 + c_off) * 256 + row * 8 + s4);

  vfloat4 aw = {0.f, 0.f, 0.f, 0.f};
  vfloat4 ah = {0.f, 0.f, 0.f, 0.f};
#pragma unroll 8
  for (int it = 0; it < 32; ++it) {
    const int c = it * 32 + c_off;
    const vfloat4 v = f4[(size_t)it * 32 * 256];
    aw += v * lw[c];
    ah += v * lh[c];
  }
  part_w[c_off][s4] = (float4){aw.x, aw.y, aw.z, aw.w};
  part_h[c_off][s4] = (float4){ah.x, ah.y, ah.z, ah.w};
  __syncthreads();

  if (t < 8) {
    const float scale_w = gw[0] * rsqrtf(vw[0] + BN_EPS);
    const float shift_w = (bw[0] - mw[0]) * scale_w + betw[0];
    const float scale_h = gh[0] * rsqrtf(vh[0] + BN_EPS);
    const float shift_h = (bh[0] - mh[0]) * scale_h + beth[0];

    float4 cw = {0.f, 0.f, 0.f, 0.f};
    float4 ch = {0.f, 0.f, 0.f, 0.f};
#pragma unroll
    for (int g = 0; g < 32; ++g) {
      const float4 pw = part_w[g][t];
      const float4 ph = part_h[g][t];
      cw.x += pw.x; cw.y += pw.y; cw.z += pw.z; cw.w += pw.w;
      ch.x += ph.x; ch.y += ph.y; ch.z += ph.z; ch.w += ph.w;
    }
    float aws = fmaxf(fmaf(cw.x, scale_w, shift_w), 0.f) +
                fmaxf(fmaf(cw.y, scale_w, shift_w), 0.f) +
                fmaxf(fmaf(cw.z, scale_w, shift_w), 0.f) +
                fmaxf(fmaf(cw.w, scale_w, shift_w), 0.f);
    const float ahs = fmaxf(fmaf(ch.x, scale_h, shift_h), 0.f) +
                      fmaxf(fmaf(ch.y, scale_h, shift_h), 0.f) +
                      fmaxf(fmaf(ch.z, scale_h, shift_h), 0.f) +
                      fmaxf(fmaf(ch.w, scale_h, shift_h), 0.f);
    // lane t (<8) covers h = 4t..4t+3 -> kh = t>>2
    const int kh = t >> 2;
    float v0 = kh == 0 ? ahs : 0.f;
    float v1 = kh == 1 ? ahs : 0.f;
#pragma unroll
    for (int off = 4; off >= 1; off >>= 1) {
      aws += __shfl_xor(aws, off);
      v0 += __shfl_xor(v0, off);
      v1 += __shfl_xor(v1, off);
    }
    if (t == 0) {
      part[b * 32 + row] = (float4){aws, v0, v1, 0.f};  // plain store
    }
  }
}

// Elementwise output pass, 4096 blocks x 256 threads, contiguous 32 KB span
// per block (i = blk*2048 + k*256 + t, k=0..7). Each wave recomputes its
// batch's factors from part[] (512 B butterfly reduce); b = blk>>7 is
// block-uniform; kw = bit7(t), kh = bit2(t) as k*256 only touches bits >= 8.
__global__ __launch_bounds__(256) void k_out(
    const float* __restrict__ fm, const float4* __restrict__ part,
    float* __restrict__ out0, float* __restrict__ out1) {
  const int t = threadIdx.x;
  const int blk = blockIdx.x;
  const int b = blk >> 7;  // block-uniform batch
  const size_t base = (size_t)blk * 2048 + t;
  const vfloat4* fm4 = reinterpret_cast<const vfloat4*>(fm);
  vfloat4* o0 = reinterpret_cast<vfloat4*>(out0);
  vfloat4* o1 = reinterpret_cast<vfloat4*>(out1);

  // issue all 8 main loads first so they overlap the factor computation
  vfloat4 v[8];
#pragma unroll
  for (int k = 0; k < 8; ++k) v[k] = fm4[base + (size_t)k * 256];

  // ---- per-wave factor recomputation ----
  const int l = t & 63;
  float sw0 = 0.f, sw1 = 0.f, h0 = 0.f, h1 = 0.f;
  if (l < 32) {
    const float4 p = part[b * 32 + l];
    if (l < 16) sw0 = p.x; else sw1 = p.x;
    h0 = p.y;
    h1 = p.z;
  }
#pragma unroll
  for (int off = 32; off >= 1; off >>= 1) {
    sw0 += __shfl_xor(sw0, off);
    sw1 += __shfl_xor(sw1, off);
    h0 += __shfl_xor(h0, off);
    h1 += __shfl_xor(h1, off);
  }
  const float pw0 = sw0 * (1.f / 512.f), pw1 = sw1 * (1.f / 512.f);
  const float ph0 = h0 * (1.f / 512.f), ph1 = h1 * (1.f / 512.f);
  const float mwv = fmaxf(pw0, pw1);
  const float ew0 = __expf(pw0 - mwv), ew1 = __expf(pw1 - mwv);
  const float s0 = ew0 / (ew0 + ew1), s1 = ew1 / (ew0 + ew1);
  const float mhv = fmaxf(ph0, ph1);
  const float eh0 = __expf(ph0 - mhv), eh1 = __expf(ph1 - mhv);
  const float t0 = eh0 / (eh0 + eh1), t1 = eh1 / (eh0 + eh1);
  const float f00 = s0 * t0, f01 = s0 * t1, f10 = s1 * t0, f11 = s1 * t1;
  const float thr = fmaxf(fmaxf(f00, f01), fmaxf(f10, f11)) * 0.95f;
  const int kw = (t >> 7) & 1;
  const int kh = (t >> 2) & 1;
  const float fq = kw ? (kh ? f11 : f10) : (kh ? f01 : f00);
  const float boost = 1.f + ALPHA * fq;
  const float mask = (fq < thr) ? 1.f : BETA;

#pragma unroll
  for (int k = 0; k < 8; ++k) {
    __builtin_nontemporal_store(v[k] * boost, &o0[base + (size_t)k * 256]);
  }
#pragma unroll
  for (int k = 0; k < 8; ++k) {
    __builtin_nontemporal_store(v[k] * mask, &o1[base + (size_t)k * 256]);
  }
}

extern "C" void kernel_launch(void* const* d_in, const int* in_sizes, int n_in,
                              void* d_out, int out_size, void* d_ws,
                              size_t ws_size, hipStream_t stream) {
  const float* fm = (const float*)d_in[0];
  const float* w_w = (const float*)d_in[1];
  const float* b_w = (const float*)d_in[2];
  const float* g_w = (const float*)d_in[3];
  const float* be_w = (const float*)d_in[4];
  const float* m_w = (const float*)d_in[5];
  const float* v_w = (const float*)d_in[6];
  const float* w_h = (const float*)d_in[7];
  const float* b_h = (const float*)d_in[8];
  const float* g_h = (const float*)d_in[9];
  const float* be_h = (const float*)d_in[10];
  const float* m_h = (const float*)d_in[11];
  const float* v_h = (const float*)d_in[12];

  char* ws = (char*)d_ws;
  float4* part = (float4*)(ws + 0);  // 16 KB, fully rewritten each call

  float* out0 = (float*)d_out;
  float* out1 = out0 + (size_t)32 * 1024 * 1024;

  k_conv<<<32 * 32, 256, 0, stream>>>(fm, w_w, w_h, b_w, g_w, be_w, m_w, v_w,
                                      b_h, g_h, be_h, m_h, v_h, part);
  k_out<<<4096, 256, 0, stream>>>(fm, part, out0, out1);
}